// Round 14
// baseline (409.497 us; speedup 1.0000x reference)
//
#include <hip/hip_runtime.h>
#include <hip/hip_fp16.h>

// NOTE (r11/r12): cooperative mega-kernels regressed 2-6x (compiler pins the
// fused grid-stride gather body at VGPR 32, serializing the 16-deep MLP
// pipeline). Props stay standalone single-shot kernels. This round cuts
// dispatches non-cooperatively: stats fused into prop1's epilogue (reduced in
// gemm2's prologue), hist+off+scatter fused into one k_bin via fixed-capacity
// window regions.

#define NNODES 100000
#define NEDGES 1600000
#define NSUB   1000

#define WSHIFT 9                         // 512-node dst windows
#define WIN    512
#define NWIN   196                       // ceil(100000/512)
#define WCAP   10240                     // window capacity (mean 8163, +23 sigma)
#define NBLK   256                       // blocks for binning
#define CHUNK  (NEDGES / NBLK)           // 6250 exact

typedef _Float16 f16x8 __attribute__((ext_vector_type(8)));
typedef float    f32x4 __attribute__((ext_vector_type(4)));

// ---------------- single-pass edge binning ----------------
// Per block: LDS histogram of its chunk -> reserve contiguous subranges in
// each window's fixed region via one global atomicAdd per (block,window) ->
// rescan chunk scattering edges into the reserved slots. Window w's edges
// end up contiguous in esw[w*WCAP .. w*WCAP+wcur[w]). Also marks
// head-needed nodes (flags==1 exact compare; no memset needed — spurious
// matches only cause harmless extra work in prop2).

__global__ __launch_bounds__(256) void k_bin(const int* __restrict__ src,
                                             const int* __restrict__ dst,
                                             const float* __restrict__ ew,
                                             int* __restrict__ wcur,
                                             int2* __restrict__ esw,
                                             const int* __restrict__ subg,
                                             int* __restrict__ flags) {
    __shared__ int hist[NWIN];
    __shared__ int base[NWIN];
    __shared__ int fill[NWIN];
    int t = threadIdx.x, b = blockIdx.x;
    if (t < 250) flags[subg[b * 250 + t]] = 1;    // 256*250 = 64000 exact
    for (int i = t; i < NWIN; i += 256) { hist[i] = 0; fill[i] = 0; }
    __syncthreads();
    int e0 = b * CHUNK;
    for (int e = e0 + t; e < e0 + CHUNK; e += 256)
        atomicAdd(&hist[dst[e] >> WSHIFT], 1);
    __syncthreads();
    for (int i = t; i < NWIN; i += 256) {
        int c = hist[i];
        base[i] = c ? atomicAdd(&wcur[i], c) : 0;
    }
    __syncthreads();
    for (int e = e0 + t; e < e0 + CHUNK; e += 256) {
        int d = dst[e];
        int w = d >> WSHIFT;
        int pos = base[w] + atomicAdd(&fill[w], 1);
        if (pos < WCAP) {
            int dl = d - (w << WSHIFT);
            esw[(size_t)w * WCAP + pos] =
                make_int2((dl << 17) | src[e], __float_as_int(ew[e]));
        }
    }
}

// one block per window: dense per-node CSR (4 B packed: wq15<<17 | src17) +
// raw-weight degree sums -> dinv. Positions are window-region-absolute.
__global__ __launch_bounds__(256) void k_fill2(const int* __restrict__ wcur,
                                               const int2* __restrict__ esw,
                                               unsigned* __restrict__ edges,
                                               int* __restrict__ row_ptr,
                                               int* __restrict__ cnt,
                                               float* __restrict__ dinv) {
    __shared__ int   cnt_l[WIN];
    __shared__ int   sc[WIN];
    __shared__ int   fill_l[WIN];
    __shared__ float degw[WIN];
    int t = threadIdx.x, w = blockIdx.x;
    #pragma unroll
    for (int i = t; i < WIN; i += 256) { cnt_l[i] = 0; fill_l[i] = 0; degw[i] = 0.f; }
    __syncthreads();
    int e0 = w * WCAP;
    int count = wcur[w]; if (count > WCAP) count = WCAP;
    int e1 = e0 + count;
    for (int e = e0 + t; e < e1; e += 256) {
        int2 v = esw[e];
        int dl = ((unsigned)v.x) >> 17;
        atomicAdd(&cnt_l[dl], 1);
        atomicAdd(&degw[dl], __int_as_float(v.y));
    }
    __syncthreads();
    sc[t] = cnt_l[t]; sc[t + 256] = cnt_l[t + 256];
    __syncthreads();
    for (int off = 1; off < WIN; off <<= 1) {
        int v0 = (t >= off) ? sc[t - off] : 0;
        int v1 = (t + 256 >= off) ? sc[t + 256 - off] : 0;
        __syncthreads();
        sc[t] += v0; sc[t + 256] += v1;
        __syncthreads();
    }
    sc[t]       = e0 + sc[t]       - cnt_l[t];
    sc[t + 256] = e0 + sc[t + 256] - cnt_l[t + 256];
    __syncthreads();
    for (int e = e0 + t; e < e1; e += 256) {
        int2 v = esw[e];
        int dl = ((unsigned)v.x) >> 17;
        int pos = sc[dl] + atomicAdd(&fill_l[dl], 1);
        int wq = __float2int_rn(__int_as_float(v.y) * 32767.0f);
        edges[pos] = ((unsigned)wq << 17) | ((unsigned)v.x & 0x1FFFFu);
    }
    __syncthreads();
    #pragma unroll
    for (int i = t; i < WIN; i += 256) {
        int node = (w << WSHIFT) + i;
        if (node < NNODES) {
            row_ptr[node] = sc[i];
            cnt[node]     = cnt_l[i];
            dinv[node]    = rsqrtf(degw[i] + 1.0f);
        }
    }
}

// ---------------- MFMA GEMM: [200000 x 64] @ [64 x 64] -> fp16, row-scaled --
// Wave = one 16x64 tile, K=64: 8 x mfma_f32_16x16x32_f16. TR=true reduces the
// 64-way stats partials in its prologue and computes GraphNorm coefs.

template <bool TR>
__global__ __launch_bounds__(256) void k_gemm(const void* __restrict__ Xv,
                                              const float* __restrict__ Wg,
                                              const float* __restrict__ dinv,
                                              _Float16* __restrict__ Y,
                                              const float* __restrict__ partial,
                                              const float* __restrict__ gn_w,
                                              const float* __restrict__ gn_b,
                                              const float* __restrict__ gn_ms) {
    __shared__ __align__(16) _Float16 ob[4][16 * 72];   // per-wave 16x64 (+pad 8)
    __shared__ float st[256];
    int t = threadIdx.x;
    int wave = t >> 6, lane = t & 63;
    int m = lane & 15, q = lane >> 4;

    if constexpr (TR) {
        float s = 0.f;
        #pragma unroll 4
        for (int j = 0; j < 64; j++) s += partial[j * 256 + t];   // coalesced, L2-hot
        st[t] = s;
    }

    // B fragments: B[k = kb*32 + q*8 + j][n = nt*16 + m]
    f16x8 bf[2][4];
    #pragma unroll
    for (int kb = 0; kb < 2; kb++)
        #pragma unroll
        for (int nt = 0; nt < 4; nt++)
            #pragma unroll
            for (int j = 0; j < 8; j++)
                bf[kb][nt][j] = (_Float16)Wg[(kb * 32 + q * 8 + j) * 64 + nt * 16 + m];

    float ca[16], cb[16];
    if constexpr (TR) {
        __syncthreads();
        int c = m & 1;     // row = n*2+c -> channel = m & 1
        const float inv_n = 1.0f / (float)NNODES;
        #pragma unroll
        for (int kb = 0; kb < 2; kb++)
            #pragma unroll
            for (int j = 0; j < 8; j++) {
                int k = kb * 32 + q * 8 + j;
                int col = c * 64 + k;
                float mean = st[col] * inv_n;
                float eh2  = st[128 + col] * inv_n;
                float ms   = gn_ms[k];
                float mm   = ms * mean;
                float var  = eh2 - 2.0f * mm * mean + mm * mm;
                float A = gn_w[k] * rsqrtf(var + 1e-5f);
                ca[kb * 8 + j] = A;
                cb[kb * 8 + j] = gn_b[k] - A * mm;
            }
    }

    int tile = blockIdx.x * 4 + wave;
    int row0 = tile * 16;

    f16x8 af[2];
    if constexpr (!TR) {
        const float* xp = (const float*)Xv + (size_t)(row0 + m) * 64;
        #pragma unroll
        for (int kb = 0; kb < 2; kb++) {
            float4 u0 = *(const float4*)(xp + kb * 32 + q * 8);
            float4 u1 = *(const float4*)(xp + kb * 32 + q * 8 + 4);
            af[kb][0] = (_Float16)u0.x; af[kb][1] = (_Float16)u0.y;
            af[kb][2] = (_Float16)u0.z; af[kb][3] = (_Float16)u0.w;
            af[kb][4] = (_Float16)u1.x; af[kb][5] = (_Float16)u1.y;
            af[kb][6] = (_Float16)u1.z; af[kb][7] = (_Float16)u1.w;
        }
    } else {
        const _Float16* xp = (const _Float16*)Xv + (size_t)(row0 + m) * 64;
        #pragma unroll
        for (int kb = 0; kb < 2; kb++) {
            f16x8 v = *(const f16x8*)(xp + kb * 32 + q * 8);
            #pragma unroll
            for (int j = 0; j < 8; j++) {
                float f = (float)v[j];
                f = fmaxf(ca[kb * 8 + j] * f + cb[kb * 8 + j], 0.0f);
                af[kb][j] = (_Float16)f;
            }
        }
    }

    f32x4 acc[4];
    #pragma unroll
    for (int nt = 0; nt < 4; nt++) {
        acc[nt] = (f32x4){0.f, 0.f, 0.f, 0.f};
        acc[nt] = __builtin_amdgcn_mfma_f32_16x16x32_f16(af[0], bf[0][nt], acc[nt], 0, 0, 0);
        acc[nt] = __builtin_amdgcn_mfma_f32_16x16x32_f16(af[1], bf[1][nt], acc[nt], 0, 0, 0);
    }

    float dv[4];
    #pragma unroll
    for (int i = 0; i < 4; i++) dv[i] = dinv[(row0 + q * 4 + i) >> 1];

    _Float16* obw = ob[wave];
    #pragma unroll
    for (int nt = 0; nt < 4; nt++)
        #pragma unroll
        for (int i = 0; i < 4; i++)
            obw[(q * 4 + i) * 72 + nt * 16 + m] = (_Float16)(acc[nt][i] * dv[i]);
    __syncthreads();

    _Float16* yp = Y + (size_t)row0 * 64;
    #pragma unroll
    for (int s = 0; s < 2; s++) {
        int c8 = s * 64 + lane;
        int r = c8 >> 3, cg2 = c8 & 7;
        uint4 v = *(const uint4*)(obw + r * 72 + cg2 * 8);
        *(uint4*)(yp + (size_t)r * 64 + cg2 * 8) = v;
    }
}

// ---------------- pull-style GCN aggregation (fp16, packed dense CSR) ------
// agg[n] = dinv[n] * (hw'[n] + sum_e ew_e * hw'[src_e]) + bias
// STATS (layer 1): fused GraphNorm (sum, sumsq) per column via block-LDS
// reduction + 64-way-spread global atomics into `partial`.
// USE_FLAGS (layer 2): skip nodes not referenced by any subgraph.
// Grid is exactly 25000*4 waves = 100000 nodes -> no bounds check.

template <bool USE_FLAGS, bool STATS>
__global__ __launch_bounds__(256) void k_prop(const __half* __restrict__ hw,
                                              const float* __restrict__ bias,
                                              const float* __restrict__ dinv,
                                              const int* __restrict__ row_ptr,
                                              const int* __restrict__ cnt,
                                              const unsigned* __restrict__ edges,
                                              const int* __restrict__ flags,
                                              __half* __restrict__ agg,
                                              float* __restrict__ partial) {
    __shared__ float ssum[128];
    __shared__ float ssq[128];
    int t = threadIdx.x;
    int lane = t & 63;
    int n = __builtin_amdgcn_readfirstlane(blockIdx.x * 4 + (t >> 6));

    if constexpr (STATS) {
        if (t < 128) ssum[t] = 0.f; else ssq[t - 128] = 0.f;
        __syncthreads();
    }
    if constexpr (USE_FLAGS) { if (flags[n] != 1) return; }

    int f = lane * 2;            // flat half-offset in [0,128), even
    int feat = f & 63;
    const float qs = 1.0f / 32767.0f;

    float2 bv = *(const float2*)(bias + feat);
    float dv = dinv[n];
    float2 self = __half22float2(*(const __half2*)(hw + (size_t)n * 128 + f));
    float acc0 = self.x;
    float acc1 = self.y;

    int start = row_ptr[n];
    int cn    = cnt[n];
    const unsigned* pp = edges + start;

    int full = cn & ~15;
    int p = 0;
    for (; p < full; p += 16) {
        unsigned e[16];
        #pragma unroll
        for (int i = 0; i < 16; i++) e[i] = pp[p + i];
        float2 h[16];
        #pragma unroll
        for (int i = 0; i < 16; i++) {
            int s = (int)(e[i] & 0x1FFFFu);
            h[i] = __half22float2(*(const __half2*)(hw + (size_t)s * 128 + f));
        }
        #pragma unroll
        for (int i = 0; i < 16; i++) {
            float w = (float)(e[i] >> 17) * qs;
            acc0 += w * h[i].x;
            acc1 += w * h[i].y;
        }
    }
    if (p < cn) {
        unsigned e[16];
        #pragma unroll
        for (int i = 0; i < 16; i++) e[i] = pp[p + i];
        float2 h[16];
        #pragma unroll
        for (int i = 0; i < 16; i++) {
            int s = (int)(e[i] & 0x1FFFFu);
            h[i] = __half22float2(*(const __half2*)(hw + (size_t)s * 128 + f));
        }
        #pragma unroll
        for (int i = 0; i < 16; i++) {
            float w = ((p + i) < cn) ? (float)(e[i] >> 17) * qs : 0.0f;
            acc0 += w * h[i].x;
            acc1 += w * h[i].y;
        }
    }

    float r0 = dv * acc0 + bv.x;
    float r1 = dv * acc1 + bv.y;
    *(__half2*)(agg + (size_t)n * 128 + f) = __floats2half2_rn(r0, r1);

    if constexpr (STATS) {
        atomicAdd(&ssum[f], r0);     atomicAdd(&ssum[f + 1], r1);
        atomicAdd(&ssq[f], r0 * r0); atomicAdd(&ssq[f + 1], r1 * r1);
        __syncthreads();
        float v = (t < 128) ? ssum[t] : ssq[t - 128];
        atomicAdd(&partial[(blockIdx.x & 63) * 256 + t], v);
    }
}

// ---------------- fused subgraph pooling + MLP head ----------------

__global__ __launch_bounds__(256) void k_head(const __half* __restrict__ agg,
                                              const int* __restrict__ subg,
                                              const float* __restrict__ mW1,
                                              const float* __restrict__ mb1,
                                              const float* __restrict__ mW2,
                                              const float* __restrict__ mb2,
                                              float* __restrict__ out) {
    __shared__ int   idx[64];
    __shared__ float pl[4][64];
    __shared__ float red[128];
    int s = blockIdx.x, t = threadIdx.x;
    if (t < 64) idx[t] = subg[s * 64 + t];
    __syncthreads();
    int j = t & 63, grp = t >> 6;
    float acc = 0.f;
    #pragma unroll
    for (int m = grp * 16; m < grp * 16 + 16; m++) {
        int n = idx[m];
        acc += __half2float(agg[(size_t)n * 128 + j]) +
               __half2float(agg[(size_t)n * 128 + 64 + j]);
    }
    pl[grp][j] = acc * 0.5f;
    __syncthreads();
    if (t < 64) pl[0][t] = pl[0][t] + pl[1][t] + pl[2][t] + pl[3][t];
    __syncthreads();
    if (t < 128) {
        float h = mb1[t];
        #pragma unroll
        for (int k = 0; k < 64; k++) h += pl[0][k] * mW1[k * 128 + t];
        h = fmaxf(h, 0.0f);
        red[t] = h * mW2[t];
    }
    __syncthreads();
    for (int off = 64; off > 0; off >>= 1) {
        if (t < off) red[t] += red[t + off];
        __syncthreads();
    }
    if (t == 0) out[s] = red[0] + mb2[0];
}

// ---------------- launcher ----------------

extern "C" void kernel_launch(void* const* d_in, const int* in_sizes, int n_in,
                              void* d_out, int out_size, void* d_ws, size_t ws_size,
                              hipStream_t stream) {
    const float* x     = (const float*)d_in[0];
    const int*   ei    = (const int*)d_in[1];
    const float* ew    = (const float*)d_in[2];
    const int*   subg  = (const int*)d_in[3];
    const float* W1    = (const float*)d_in[4];
    const float* b1    = (const float*)d_in[5];
    const float* gn_w  = (const float*)d_in[6];
    const float* gn_b  = (const float*)d_in[7];
    const float* gn_ms = (const float*)d_in[8];
    const float* W2    = (const float*)d_in[9];
    const float* b2    = (const float*)d_in[10];
    const float* mW1   = (const float*)d_in[11];
    const float* mb1   = (const float*)d_in[12];
    const float* mW2   = (const float*)d_in[13];
    const float* mb2   = (const float*)d_in[14];
    float* out = (float*)d_out;

    char* w = (char*)d_ws;
    size_t off = 0;
    auto alloc = [&](size_t bytes) {
        void* p = w + off;
        off = (off + bytes + 255) & ~(size_t)255;
        return p;
    };
    // wcur + partial first and adjacent: one memset zeroes both
    int*      wcur    = (int*)     alloc(NWIN * 4);
    float*    partial = (float*)   alloc(64 * 256 * 4);               // 64 KB
    float*    dinv    = (float*)   alloc((size_t)NNODES * 4);
    int*      cnt     = (int*)     alloc((size_t)NNODES * 4);
    int*      row_ptr = (int*)     alloc((size_t)NNODES * 4);
    int*      flags   = (int*)     alloc((size_t)NNODES * 4);
    unsigned* edges   = (unsigned*)alloc(((size_t)NWIN * WCAP + 64) * 4);  // 8 MB
    int2*     esw     = (int2*)    alloc((size_t)NWIN * WCAP * 8);         // 16 MB
    __half*   hw      = (__half*)  alloc((size_t)NNODES * 128 * 2);        // 25.6 MB
    __half*   agg     = (__half*)  alloc((size_t)NNODES * 128 * 2);        // 25.6 MB

    const int* src = ei;
    const int* dst = ei + NEDGES;

    size_t zspan = (size_t)((char*)(partial + 64 * 256) - (char*)wcur);
    hipMemsetAsync(wcur, 0, zspan, stream);

    // single-pass binning -> dense CSR + dinv
    k_bin  <<<NBLK, 256, 0, stream>>>(src, dst, ew, wcur, esw, subg, flags);
    k_fill2<<<NWIN, 256, 0, stream>>>(wcur, esw, edges, row_ptr, cnt, dinv);

    // layer 1 (prop fuses GraphNorm stats)
    k_gemm<false><<<3125, 256, 0, stream>>>(x, W1, dinv, (_Float16*)hw,
                                            nullptr, nullptr, nullptr, nullptr);
    k_prop<false, true><<<25000, 256, 0, stream>>>(hw, b1, dinv, row_ptr, cnt, edges,
                                                   nullptr, agg, partial);

    // layer 2 (stats reduction + GraphNorm coef + affine + ReLU fused into GEMM2)
    k_gemm<true><<<3125, 256, 0, stream>>>(agg, W2, dinv, (_Float16*)hw,
                                           partial, gn_w, gn_b, gn_ms);
    k_prop<true, false><<<25000, 256, 0, stream>>>(hw, b2, dinv, row_ptr, cnt, edges,
                                                   flags, agg, nullptr);

    // fused pooling + MLP head
    k_head<<<NSUB, 256, 0, stream>>>(agg, subg, mW1, mb1, mW2, mb2, out);
}

// Round 15
// 329.509 us; speedup vs baseline: 1.2427x; 1.2427x over previous
//
#include <hip/hip_runtime.h>
#include <hip/hip_fp16.h>

// NOTES from failed experiments (keep for future rounds):
// - r11/r12: cooperative mega-kernel fusion of prop+stats/prop+head regresses
//   2-6x — compiler pins the fused grid-stride gather body at VGPR 32 and
//   serializes the 16-deep pipeline. Props stay standalone single-shot.
// - r14: fusing GraphNorm stats into prop1's epilogue costs 6.4M device-scope
//   atomics (25000 blocks x 256; only 4 nodes/block pre-reduced) -> +25 MB HBM
//   RMW traffic, prop1 63->162 us. Standalone k_stats (512 blocks, ~8 us) wins.

#define NNODES 100000
#define NEDGES 1600000
#define NSUB   1000

#define WSHIFT 9                         // 512-node dst windows
#define WIN    512
#define NWIN   196                       // ceil(100000/512)
#define WCAP   10240                     // window capacity (mean 8163, +23 sigma)
#define NBLK   256                       // blocks for binning
#define CHUNK  (NEDGES / NBLK)           // 6250 exact

typedef _Float16 f16x8 __attribute__((ext_vector_type(8)));
typedef float    f32x4 __attribute__((ext_vector_type(4)));

// ---------------- single-pass edge binning ----------------
// Per block: LDS histogram of its chunk -> reserve contiguous subranges in
// each window's fixed region (one global atomicAdd per (block,window)) ->
// rescan chunk scattering edges into the reserved slots. Also marks
// head-needed nodes (flags==1 exact compare; no memset needed).

__global__ __launch_bounds__(256) void k_bin(const int* __restrict__ src,
                                             const int* __restrict__ dst,
                                             const float* __restrict__ ew,
                                             int* __restrict__ wcur,
                                             int2* __restrict__ esw,
                                             const int* __restrict__ subg,
                                             int* __restrict__ flags) {
    __shared__ int hist[NWIN];
    __shared__ int base[NWIN];
    __shared__ int fill[NWIN];
    int t = threadIdx.x, b = blockIdx.x;
    if (t < 250) flags[subg[b * 250 + t]] = 1;    // 256*250 = 64000 exact
    for (int i = t; i < NWIN; i += 256) { hist[i] = 0; fill[i] = 0; }
    __syncthreads();
    int e0 = b * CHUNK;
    for (int e = e0 + t; e < e0 + CHUNK; e += 256)
        atomicAdd(&hist[dst[e] >> WSHIFT], 1);
    __syncthreads();
    for (int i = t; i < NWIN; i += 256) {
        int c = hist[i];
        base[i] = c ? atomicAdd(&wcur[i], c) : 0;
    }
    __syncthreads();
    for (int e = e0 + t; e < e0 + CHUNK; e += 256) {
        int d = dst[e];
        int w = d >> WSHIFT;
        int pos = base[w] + atomicAdd(&fill[w], 1);
        if (pos < WCAP) {
            int dl = d - (w << WSHIFT);
            esw[(size_t)w * WCAP + pos] =
                make_int2((dl << 17) | src[e], __float_as_int(ew[e]));
        }
    }
}

// one block per window: dense per-node CSR (4 B packed: wq15<<17 | src17) +
// raw-weight degree sums -> dinv. Positions are window-region-absolute.
__global__ __launch_bounds__(256) void k_fill2(const int* __restrict__ wcur,
                                               const int2* __restrict__ esw,
                                               unsigned* __restrict__ edges,
                                               int* __restrict__ row_ptr,
                                               int* __restrict__ cnt,
                                               float* __restrict__ dinv) {
    __shared__ int   cnt_l[WIN];
    __shared__ int   sc[WIN];
    __shared__ int   fill_l[WIN];
    __shared__ float degw[WIN];
    int t = threadIdx.x, w = blockIdx.x;
    #pragma unroll
    for (int i = t; i < WIN; i += 256) { cnt_l[i] = 0; fill_l[i] = 0; degw[i] = 0.f; }
    __syncthreads();
    int e0 = w * WCAP;
    int count = wcur[w]; if (count > WCAP) count = WCAP;
    int e1 = e0 + count;
    for (int e = e0 + t; e < e1; e += 256) {
        int2 v = esw[e];
        int dl = ((unsigned)v.x) >> 17;
        atomicAdd(&cnt_l[dl], 1);
        atomicAdd(&degw[dl], __int_as_float(v.y));
    }
    __syncthreads();
    sc[t] = cnt_l[t]; sc[t + 256] = cnt_l[t + 256];
    __syncthreads();
    for (int off = 1; off < WIN; off <<= 1) {
        int v0 = (t >= off) ? sc[t - off] : 0;
        int v1 = (t + 256 >= off) ? sc[t + 256 - off] : 0;
        __syncthreads();
        sc[t] += v0; sc[t + 256] += v1;
        __syncthreads();
    }
    sc[t]       = e0 + sc[t]       - cnt_l[t];
    sc[t + 256] = e0 + sc[t + 256] - cnt_l[t + 256];
    __syncthreads();
    for (int e = e0 + t; e < e1; e += 256) {
        int2 v = esw[e];
        int dl = ((unsigned)v.x) >> 17;
        int pos = sc[dl] + atomicAdd(&fill_l[dl], 1);
        int wq = __float2int_rn(__int_as_float(v.y) * 32767.0f);
        edges[pos] = ((unsigned)wq << 17) | ((unsigned)v.x & 0x1FFFFu);
    }
    __syncthreads();
    #pragma unroll
    for (int i = t; i < WIN; i += 256) {
        int node = (w << WSHIFT) + i;
        if (node < NNODES) {
            row_ptr[node] = sc[i];
            cnt[node]     = cnt_l[i];
            dinv[node]    = rsqrtf(degw[i] + 1.0f);
        }
    }
}

// ---------------- MFMA GEMM: [200000 x 64] @ [64 x 64] -> fp16, row-scaled --
// Wave = one 16x64 tile, K=64: 8 x mfma_f32_16x16x32_f16. TR=true computes
// GraphNorm coefs per-thread from stats.

template <bool TR>
__global__ __launch_bounds__(256) void k_gemm(const void* __restrict__ Xv,
                                              const float* __restrict__ Wg,
                                              const float* __restrict__ dinv,
                                              _Float16* __restrict__ Y,
                                              const float* __restrict__ stats,
                                              const float* __restrict__ gn_w,
                                              const float* __restrict__ gn_b,
                                              const float* __restrict__ gn_ms) {
    __shared__ __align__(16) _Float16 ob[4][16 * 72];   // per-wave 16x64 (+pad 8)
    int t = threadIdx.x;
    int wave = t >> 6, lane = t & 63;
    int m = lane & 15, q = lane >> 4;

    // B fragments: B[k = kb*32 + q*8 + j][n = nt*16 + m]
    f16x8 bf[2][4];
    #pragma unroll
    for (int kb = 0; kb < 2; kb++)
        #pragma unroll
        for (int nt = 0; nt < 4; nt++)
            #pragma unroll
            for (int j = 0; j < 8; j++)
                bf[kb][nt][j] = (_Float16)Wg[(kb * 32 + q * 8 + j) * 64 + nt * 16 + m];

    float ca[16], cb[16];
    if constexpr (TR) {
        int c = m & 1;     // row = n*2+c -> channel = m & 1
        const float inv_n = 1.0f / (float)NNODES;
        #pragma unroll
        for (int kb = 0; kb < 2; kb++)
            #pragma unroll
            for (int j = 0; j < 8; j++) {
                int k = kb * 32 + q * 8 + j;
                int col = c * 64 + k;
                float mean = stats[col] * inv_n;
                float eh2  = stats[128 + col] * inv_n;
                float ms   = gn_ms[k];
                float mm   = ms * mean;
                float var  = eh2 - 2.0f * mm * mean + mm * mm;
                float A = gn_w[k] * rsqrtf(var + 1e-5f);
                ca[kb * 8 + j] = A;
                cb[kb * 8 + j] = gn_b[k] - A * mm;
            }
    }

    int tile = blockIdx.x * 4 + wave;
    int row0 = tile * 16;

    f16x8 af[2];
    if constexpr (!TR) {
        const float* xp = (const float*)Xv + (size_t)(row0 + m) * 64;
        #pragma unroll
        for (int kb = 0; kb < 2; kb++) {
            float4 u0 = *(const float4*)(xp + kb * 32 + q * 8);
            float4 u1 = *(const float4*)(xp + kb * 32 + q * 8 + 4);
            af[kb][0] = (_Float16)u0.x; af[kb][1] = (_Float16)u0.y;
            af[kb][2] = (_Float16)u0.z; af[kb][3] = (_Float16)u0.w;
            af[kb][4] = (_Float16)u1.x; af[kb][5] = (_Float16)u1.y;
            af[kb][6] = (_Float16)u1.z; af[kb][7] = (_Float16)u1.w;
        }
    } else {
        const _Float16* xp = (const _Float16*)Xv + (size_t)(row0 + m) * 64;
        #pragma unroll
        for (int kb = 0; kb < 2; kb++) {
            f16x8 v = *(const f16x8*)(xp + kb * 32 + q * 8);
            #pragma unroll
            for (int j = 0; j < 8; j++) {
                float f = (float)v[j];
                f = fmaxf(ca[kb * 8 + j] * f + cb[kb * 8 + j], 0.0f);
                af[kb][j] = (_Float16)f;
            }
        }
    }

    f32x4 acc[4];
    #pragma unroll
    for (int nt = 0; nt < 4; nt++) {
        acc[nt] = (f32x4){0.f, 0.f, 0.f, 0.f};
        acc[nt] = __builtin_amdgcn_mfma_f32_16x16x32_f16(af[0], bf[0][nt], acc[nt], 0, 0, 0);
        acc[nt] = __builtin_amdgcn_mfma_f32_16x16x32_f16(af[1], bf[1][nt], acc[nt], 0, 0, 0);
    }

    float dv[4];
    #pragma unroll
    for (int i = 0; i < 4; i++) dv[i] = dinv[(row0 + q * 4 + i) >> 1];

    _Float16* obw = ob[wave];
    #pragma unroll
    for (int nt = 0; nt < 4; nt++)
        #pragma unroll
        for (int i = 0; i < 4; i++)
            obw[(q * 4 + i) * 72 + nt * 16 + m] = (_Float16)(acc[nt][i] * dv[i]);
    __syncthreads();

    _Float16* yp = Y + (size_t)row0 * 64;
    #pragma unroll
    for (int s = 0; s < 2; s++) {
        int c8 = s * 64 + lane;
        int r = c8 >> 3, cg2 = c8 & 7;
        uint4 v = *(const uint4*)(obw + r * 72 + cg2 * 8);
        *(uint4*)(yp + (size_t)r * 64 + cg2 * 8) = v;
    }
}

// ---------------- pull-style GCN aggregation (fp16, packed dense CSR) ------
// agg[n] = dinv[n] * (hw'[n] + sum_e ew_e * hw'[src_e]) + bias
// USE_FLAGS (layer 2): skip nodes not referenced by any subgraph.
// Tail batch over-reads within the window region (masked weights).

template <bool USE_FLAGS>
__global__ __launch_bounds__(256) void k_prop(const __half* __restrict__ hw,
                                              const float* __restrict__ bias,
                                              const float* __restrict__ dinv,
                                              const int* __restrict__ row_ptr,
                                              const int* __restrict__ cnt,
                                              const unsigned* __restrict__ edges,
                                              const int* __restrict__ flags,
                                              __half* __restrict__ agg) {
    int t = threadIdx.x;
    int lane = t & 63;
    int n = __builtin_amdgcn_readfirstlane(blockIdx.x * 4 + (t >> 6));
    if constexpr (USE_FLAGS) { if (flags[n] != 1) return; }

    int f = lane * 2;            // flat half-offset in [0,128), even
    int feat = f & 63;
    const float qs = 1.0f / 32767.0f;

    float2 bv = *(const float2*)(bias + feat);
    float dv = dinv[n];
    float2 self = __half22float2(*(const __half2*)(hw + (size_t)n * 128 + f));
    float acc0 = self.x;
    float acc1 = self.y;

    int start = row_ptr[n];
    int cn    = cnt[n];
    const unsigned* pp = edges + start;

    int full = cn & ~15;
    int p = 0;
    for (; p < full; p += 16) {
        unsigned e[16];
        #pragma unroll
        for (int i = 0; i < 16; i++) e[i] = pp[p + i];
        float2 h[16];
        #pragma unroll
        for (int i = 0; i < 16; i++) {
            int s = (int)(e[i] & 0x1FFFFu);
            h[i] = __half22float2(*(const __half2*)(hw + (size_t)s * 128 + f));
        }
        #pragma unroll
        for (int i = 0; i < 16; i++) {
            float w = (float)(e[i] >> 17) * qs;
            acc0 += w * h[i].x;
            acc1 += w * h[i].y;
        }
    }
    if (p < cn) {
        unsigned e[16];
        #pragma unroll
        for (int i = 0; i < 16; i++) e[i] = pp[p + i];
        float2 h[16];
        #pragma unroll
        for (int i = 0; i < 16; i++) {
            int s = (int)(e[i] & 0x1FFFFu);
            h[i] = __half22float2(*(const __half2*)(hw + (size_t)s * 128 + f));
        }
        #pragma unroll
        for (int i = 0; i < 16; i++) {
            float w = ((p + i) < cn) ? (float)(e[i] >> 17) * qs : 0.0f;
            acc0 += w * h[i].x;
            acc1 += w * h[i].y;
        }
    }

    *(__half2*)(agg + (size_t)n * 128 + f) =
        __floats2half2_rn(dv * acc0 + bv.x, dv * acc1 + bv.y);
}

// ---------------- GraphNorm stats (sum, sumsq per column) ----------------

__global__ __launch_bounds__(256) void k_stats(const __half* __restrict__ agg,
                                               float* __restrict__ stats) {
    __shared__ float ls[16][128];
    __shared__ float lq[16][128];
    int t = threadIdx.x;
    int cb = (t & 15) * 8;
    int rg = t >> 4;
    float s[8], q[8];
    #pragma unroll
    for (int i = 0; i < 8; i++) { s[i] = 0.f; q[i] = 0.f; }
    for (int r = blockIdx.x * 16 + rg; r < NNODES; r += gridDim.x * 16) {
        uint4 u = *(const uint4*)(agg + (size_t)r * 128 + cb);
        const __half2* h2 = (const __half2*)&u;
        #pragma unroll
        for (int i = 0; i < 4; i++) {
            float2 v = __half22float2(h2[i]);
            s[2*i]   += v.x; q[2*i]   += v.x * v.x;
            s[2*i+1] += v.y; q[2*i+1] += v.y * v.y;
        }
    }
    #pragma unroll
    for (int i = 0; i < 8; i++) { ls[rg][cb + i] = s[i]; lq[rg][cb + i] = q[i]; }
    __syncthreads();
    if (t < 128) {
        float a = 0.f, b = 0.f;
        #pragma unroll
        for (int g = 0; g < 16; g++) { a += ls[g][t]; b += lq[g][t]; }
        atomicAdd(&stats[t], a);
        atomicAdd(&stats[128 + t], b);
    }
}

// ---------------- fused subgraph pooling + MLP head ----------------

__global__ __launch_bounds__(256) void k_head(const __half* __restrict__ agg,
                                              const int* __restrict__ subg,
                                              const float* __restrict__ mW1,
                                              const float* __restrict__ mb1,
                                              const float* __restrict__ mW2,
                                              const float* __restrict__ mb2,
                                              float* __restrict__ out) {
    __shared__ int   idx[64];
    __shared__ float pl[4][64];
    __shared__ float red[128];
    int s = blockIdx.x, t = threadIdx.x;
    if (t < 64) idx[t] = subg[s * 64 + t];
    __syncthreads();
    int j = t & 63, grp = t >> 6;
    float acc = 0.f;
    #pragma unroll
    for (int m = grp * 16; m < grp * 16 + 16; m++) {
        int n = idx[m];
        acc += __half2float(agg[(size_t)n * 128 + j]) +
               __half2float(agg[(size_t)n * 128 + 64 + j]);
    }
    pl[grp][j] = acc * 0.5f;
    __syncthreads();
    if (t < 64) pl[0][t] = pl[0][t] + pl[1][t] + pl[2][t] + pl[3][t];
    __syncthreads();
    if (t < 128) {
        float h = mb1[t];
        #pragma unroll
        for (int k = 0; k < 64; k++) h += pl[0][k] * mW1[k * 128 + t];
        h = fmaxf(h, 0.0f);
        red[t] = h * mW2[t];
    }
    __syncthreads();
    for (int off = 64; off > 0; off >>= 1) {
        if (t < off) red[t] += red[t + off];
        __syncthreads();
    }
    if (t == 0) out[s] = red[0] + mb2[0];
}

// ---------------- launcher ----------------

extern "C" void kernel_launch(void* const* d_in, const int* in_sizes, int n_in,
                              void* d_out, int out_size, void* d_ws, size_t ws_size,
                              hipStream_t stream) {
    const float* x     = (const float*)d_in[0];
    const int*   ei    = (const int*)d_in[1];
    const float* ew    = (const float*)d_in[2];
    const int*   subg  = (const int*)d_in[3];
    const float* W1    = (const float*)d_in[4];
    const float* b1    = (const float*)d_in[5];
    const float* gn_w  = (const float*)d_in[6];
    const float* gn_b  = (const float*)d_in[7];
    const float* gn_ms = (const float*)d_in[8];
    const float* W2    = (const float*)d_in[9];
    const float* b2    = (const float*)d_in[10];
    const float* mW1   = (const float*)d_in[11];
    const float* mb1   = (const float*)d_in[12];
    const float* mW2   = (const float*)d_in[13];
    const float* mb2   = (const float*)d_in[14];
    float* out = (float*)d_out;

    char* w = (char*)d_ws;
    size_t off = 0;
    auto alloc = [&](size_t bytes) {
        void* p = w + off;
        off = (off + bytes + 255) & ~(size_t)255;
        return p;
    };
    // wcur + stats adjacent: one memset zeroes both
    int*      wcur    = (int*)     alloc(NWIN * 4);
    float*    stats   = (float*)   alloc(512 * 4);
    float*    dinv    = (float*)   alloc((size_t)NNODES * 4);
    int*      cnt     = (int*)     alloc((size_t)NNODES * 4);
    int*      row_ptr = (int*)     alloc((size_t)NNODES * 4);
    int*      flags   = (int*)     alloc((size_t)NNODES * 4);
    unsigned* edges   = (unsigned*)alloc(((size_t)NWIN * WCAP + 64) * 4);  // 8 MB
    int2*     esw     = (int2*)    alloc((size_t)NWIN * WCAP * 8);         // 16 MB
    __half*   hw      = (__half*)  alloc((size_t)NNODES * 128 * 2);        // 25.6 MB
    __half*   agg     = (__half*)  alloc((size_t)NNODES * 128 * 2);        // 25.6 MB

    const int* src = ei;
    const int* dst = ei + NEDGES;

    size_t zspan = (size_t)((char*)(stats + 512) - (char*)wcur);
    hipMemsetAsync(wcur, 0, zspan, stream);

    // single-pass binning -> dense CSR + dinv
    k_bin  <<<NBLK, 256, 0, stream>>>(src, dst, ew, wcur, esw, subg, flags);
    k_fill2<<<NWIN, 256, 0, stream>>>(wcur, esw, edges, row_ptr, cnt, dinv);

    // layer 1
    k_gemm<false><<<3125, 256, 0, stream>>>(x, W1, dinv, (_Float16*)hw,
                                            nullptr, nullptr, nullptr, nullptr);
    k_prop<false><<<25000, 256, 0, stream>>>(hw, b1, dinv, row_ptr, cnt, edges,
                                             nullptr, agg);

    // GraphNorm stats
    k_stats<<<512, 256, 0, stream>>>(agg, stats);

    // layer 2 (GraphNorm coef + affine + ReLU fused into GEMM2)
    k_gemm<true><<<3125, 256, 0, stream>>>(agg, W2, dinv, (_Float16*)hw,
                                           stats, gn_w, gn_b, gn_ms);
    k_prop<true><<<25000, 256, 0, stream>>>(hw, b2, dinv, row_ptr, cnt, edges,
                                            flags, agg);

    // fused pooling + MLP head
    k_head<<<NSUB, 256, 0, stream>>>(agg, subg, mW1, mb1, mW2, mb2, out);
}